// Round 3
// baseline (336.833 us; speedup 1.0000x reference)
//
#include <hip/hip_runtime.h>

typedef __bf16 bf16_t;
typedef __bf16 bf16x8 __attribute__((ext_vector_type(8)));
typedef __bf16 bf16x4 __attribute__((ext_vector_type(4)));
typedef float  f32x4  __attribute__((ext_vector_type(4)));

// workspace layout (bf16 element offsets)
#define WB_OFF  0LL          // 3 x 1024 x 1024 bf16 weights (q,k,v)
#define XQT_OFF 3145728LL    // [b][p][c] bf16
#define XKT_OFF 11534336LL
#define Q_OFF   19922944LL   // [b][c][p] bf16
#define KT_OFF  28311552LL   // [b][p][c] bf16
#define VT_OFF  36700160LL   // [b][p][c] bf16
// total: 45088768 elems * 2B = 90.2 MB

__device__ __forceinline__ void gl_lds16(const bf16_t* g, bf16_t* l) {
  __builtin_amdgcn_global_load_lds((const __attribute__((address_space(1))) void*)(g),
                                   (__attribute__((address_space(3))) void*)(l), 16, 0, 0);
}

__device__ __forceinline__ bf16x4 cvt4(f32x4 v) {
  bf16x4 r;
  r[0] = (bf16_t)v[0]; r[1] = (bf16_t)v[1]; r[2] = (bf16_t)v[2]; r[3] = (bf16_t)v[3];
  return r;
}

// ---------------- weight convert: fp32 -> bf16 ----------------
__global__ __launch_bounds__(256) void k_wconv(
    const float* __restrict__ Wq, const float* __restrict__ Wk, const float* __restrict__ Wv,
    bf16_t* __restrict__ ws)
{
  const float* W = blockIdx.y == 0 ? Wq : (blockIdx.y == 1 ? Wk : Wv);
  bf16_t* dst = ws + WB_OFF + (long)blockIdx.y * 1048576;
  const long i = ((long)blockIdx.x * 256 + threadIdx.x) * 4;
  *(bf16x4*)&dst[i] = cvt4(*(const f32x4*)(W + i));
}

// ---------------- transpose+convert: XT[b][p][c] = bf16(X[b][c][p]) ----------------
__global__ __launch_bounds__(256) void k_transpose(
    const float* __restrict__ Xq, const float* __restrict__ Xk, bf16_t* __restrict__ ws)
{
  __shared__ __align__(16) bf16_t t[64 * 72];  // +8 pad per row (16B-aligned rows)
  const int z = blockIdx.z, b = z & 3, ts = z >> 2;
  const float* X = ts ? Xk : Xq;
  bf16_t* XT = ws + (ts ? XKT_OFF : XQT_OFF);
  const int p0 = blockIdx.x * 64, c0 = blockIdx.y * 64;
  const int tid = threadIdx.x;
  const int tx = tid & 15, ty = tid >> 4;  // tx: float4 column, ty: 0..15
  const float* src = X + ((long)b * 1024 + c0) * 2048 + p0;
  #pragma unroll
  for (int hh = 0; hh < 4; ++hh) {
    int c = ty + hh * 16;
    f32x4 v = *(const f32x4*)(src + (long)c * 2048 + tx * 4);
    *(bf16x4*)&t[c * 72 + tx * 4] = cvt4(v);
  }
  __syncthreads();
  bf16_t* dst = XT + ((long)b * 2048 + p0) * 1024 + c0;
  #pragma unroll
  for (int hh = 0; hh < 2; ++hh) {
    int p = (tid >> 3) + hh * 32;  // 0..63
    int cc = tid & 7;
    bf16x8 v;
    #pragma unroll
    for (int j = 0; j < 8; ++j) v[j] = t[(cc * 8 + j) * 72 + p];
    *(bf16x8*)(dst + (long)p * 1024 + cc * 8) = v;
  }
}

// ---------------- QKV GEMM: Y[o][p] = LeakyReLU(BN(W @ X)) ----------------
// A = Wbf [o][c] row-major; B^T = XT [p][c] row-major; both k-contiguous.
// LDS: contiguous [row][64] bf16 with XOR chunk-swizzle (global_load_lds friendly).
// Epilogue bounces through LDS: Q stored natural [o][p]; K,V stored transposed [p][o].
__global__ __launch_bounds__(256) void k_qkv(
    const float* __restrict__ g1, const float* __restrict__ b1, const float* __restrict__ m1, const float* __restrict__ v1,
    const float* __restrict__ g2, const float* __restrict__ b2, const float* __restrict__ m2, const float* __restrict__ v2,
    const float* __restrict__ g3, const float* __restrict__ b3, const float* __restrict__ m3, const float* __restrict__ v3,
    bf16_t* __restrict__ ws)
{
  __shared__ __align__(16) bf16_t smem[17408];  // staging: a[8192]+b[8192]; epilogue: 128*136
  bf16_t* sa = smem;
  bf16_t* sb = smem + 8192;
  bf16_t* ep = smem;
  __shared__ float sS[128], sBi[128];

  const int tid = threadIdx.x;
  const int z = blockIdx.z, br = z >> 2, b = z & 3;
  const int o0 = blockIdx.y * 128, p0 = blockIdx.x * 128;

  const float *gm, *bt, *mn, *vr;
  const bf16_t *XT;
  bf16_t* dst;
  int tr;
  if (br == 0)      { XT = ws + XQT_OFF; gm = g1; bt = b1; mn = m1; vr = v1; dst = ws + Q_OFF;  tr = 0; }
  else if (br == 1) { XT = ws + XKT_OFF; gm = g2; bt = b2; mn = m2; vr = v2; dst = ws + KT_OFF; tr = 1; }
  else              { XT = ws + XQT_OFF; gm = g3; bt = b3; mn = m3; vr = v3; dst = ws + VT_OFF; tr = 1; }
  const bf16_t* W = ws + WB_OFF + (long)br * 1048576;

  if (tid < 128) {
    float g = gm[o0 + tid], be = bt[o0 + tid];
    float m = mn[o0 + tid], v = vr[o0 + tid];
    float sc = g / sqrtf(v + 1e-5f);
    sS[tid] = sc; sBi[tid] = be - m * sc;
  }

  const int w = tid >> 6, lane = tid & 63, quad = lane >> 4, l15 = lane & 15;
  const int wr = (w >> 1) * 64, wc = (w & 1) * 64;

  f32x4 acc[4][4];
  #pragma unroll
  for (int i = 0; i < 4; ++i)
    #pragma unroll
    for (int j = 0; j < 4; ++j) acc[i][j] = f32x4{0.f, 0.f, 0.f, 0.f};

  const bf16_t* Wb = W + (long)o0 * 1024;
  const bf16_t* Xb = XT + ((long)b * 2048 + p0) * 1024;

  for (int kk = 0; kk < 16; ++kk) {
    __syncthreads();
    const int kof = kk * 64;
    #pragma unroll
    for (int is = 0; is < 4; ++is) {
      int s = (is * 4 + w) * 64 + lane;
      int row = s >> 3, ch = s & 7;
      int col = kof + ((ch ^ (row & 7)) << 3);
      gl_lds16(Wb + (long)row * 1024 + col, &sa[(is * 4 + w) * 512]);
      gl_lds16(Xb + (long)row * 1024 + col, &sb[(is * 4 + w) * 512]);
    }
    __syncthreads();
    #pragma unroll
    for (int ks = 0; ks < 2; ++ks) {
      bf16x8 af[4], bfr[4];
      #pragma unroll
      for (int i = 0; i < 4; ++i) {
        int mm = wr + i * 16 + l15;
        af[i] = *(const bf16x8*)&sa[mm * 64 + (((ks * 4 + quad) ^ (mm & 7)) << 3)];
        int nn = wc + i * 16 + l15;
        bfr[i] = *(const bf16x8*)&sb[nn * 64 + (((ks * 4 + quad) ^ (nn & 7)) << 3)];
      }
      #pragma unroll
      for (int i = 0; i < 4; ++i)
        #pragma unroll
        for (int j = 0; j < 4; ++j)
          acc[i][j] = __builtin_amdgcn_mfma_f32_16x16x32_bf16(af[i], bfr[j], acc[i][j], 0, 0, 0);
    }
  }

  __syncthreads();
  #pragma unroll
  for (int i = 0; i < 4; ++i) {
    #pragma unroll
    for (int j = 0; j < 4; ++j) {
      const int p_l = wc + j * 16 + l15;
      const int ob = wr + i * 16 + quad * 4;
      if (!tr) {
        #pragma unroll
        for (int r = 0; r < 4; ++r) {
          float v = fmaf(acc[i][j][r], sS[ob + r], sBi[ob + r]);
          v = v > 0.f ? v : 0.1f * v;
          ep[(ob + r) * 136 + p_l] = (bf16_t)v;
        }
      } else {
        bf16x4 t4;
        #pragma unroll
        for (int r = 0; r < 4; ++r) {
          float v = fmaf(acc[i][j][r], sS[ob + r], sBi[ob + r]);
          v = v > 0.f ? v : 0.1f * v;
          t4[r] = (bf16_t)v;
        }
        *(bf16x4*)&ep[p_l * 136 + ob] = t4;  // (p_l*136+ob)*2 is 8B-aligned
      }
    }
  }
  __syncthreads();
  #pragma unroll
  for (int pass = 0; pass < 8; ++pass) {
    int row = pass * 16 + (tid >> 4);
    int ch = tid & 15;
    bf16x8 v = *(const bf16x8*)&ep[row * 136 + ch * 8];
    long off;
    if (!tr) off = ((long)b * 1024 + o0 + row) * 2048 + p0 + ch * 8;
    else     off = ((long)b * 2048 + p0 + row) * 1024 + o0 + ch * 8;
    *(bf16x8*)&dst[off] = v;
  }
}

// ---------------- fused attention (no-max softmax, streaming) ----------------
// per block: (b, h, i-tile of 128). K-tile [128 i][128 c] resident.
// loop j-tiles: S=K^T V (MFMA), P=exp2(S*scl), l+=rowsum, P->LDS (wave-local),
// U += P Q^T (MFMA). Final: out = U/l (fp32 output). XOR-chunk-swizzled LDS, unpadded.
__global__ __launch_bounds__(512) void k_attn(const bf16_t* __restrict__ ws, float* __restrict__ out)
{
  __shared__ __align__(16) bf16_t sK[16384];
  __shared__ __align__(16) bf16_t sV[16384];
  __shared__ __align__(16) bf16_t sQ[16384];
  __shared__ __align__(16) bf16_t sP[16384];

  const int tid = threadIdx.x, w = tid >> 6, lane = tid & 63, quad = lane >> 4, l15 = lane & 15;
  const int i0 = blockIdx.x * 128, h = blockIdx.y, b = blockIdx.z;

  const bf16_t* KTb = ws + KT_OFF + ((long)b * 2048 + i0) * 1024 + h * 128;
  const bf16_t* VTb = ws + VT_OFF + ((long)b * 2048) * 1024 + h * 128;
  const bf16_t* Qb  = ws + Q_OFF  + ((long)b * 1024 + h * 128) * 2048;

  #pragma unroll
  for (int is = 0; is < 4; ++is) {
    int s = (is * 8 + w) * 64 + lane;
    int row = s >> 4, ch = s & 15;
    gl_lds16(KTb + (long)row * 1024 + ((ch ^ (row & 15)) << 3), &sK[(is * 8 + w) * 512]);
  }

  f32x4 U[8];
  #pragma unroll
  for (int f = 0; f < 8; ++f) U[f] = f32x4{0.f, 0.f, 0.f, 0.f};
  float ls[4] = {0.f, 0.f, 0.f, 0.f};

  const int irow = w * 16 + l15;                  // this wave's 16 softmax rows
  const float SCL = 1.4426950408889634f * 0.08838834764831843f;  // log2(e)/sqrt(128)

  for (int jt = 0; jt < 16; ++jt) {
    const int j0 = jt * 128;
    #pragma unroll
    for (int is = 0; is < 4; ++is) {
      int s = (is * 8 + w) * 64 + lane;
      int row = s >> 4, ch = s & 15;
      gl_lds16(VTb + (long)(j0 + row) * 1024 + ((ch ^ (row & 15)) << 3), &sV[(is * 8 + w) * 512]);
      gl_lds16(Qb + (long)row * 2048 + j0 + ((ch ^ (row & 15)) << 3), &sQ[(is * 8 + w) * 512]);
    }
    __syncthreads();

    bf16x8 af[4];
    #pragma unroll
    for (int ks = 0; ks < 4; ++ks)
      af[ks] = *(const bf16x8*)&sK[irow * 128 + (((ks * 4 + quad) ^ l15) << 3)];

    #pragma unroll
    for (int fj = 0; fj < 8; ++fj) {
      f32x4 S = f32x4{0.f, 0.f, 0.f, 0.f};
      const int jr = fj * 16 + l15;
      #pragma unroll
      for (int ks = 0; ks < 4; ++ks) {
        bf16x8 bfr = *(const bf16x8*)&sV[jr * 128 + (((ks * 4 + quad) ^ l15) << 3)];
        S = __builtin_amdgcn_mfma_f32_16x16x32_bf16(af[ks], bfr, S, 0, 0, 0);
      }
      #pragma unroll
      for (int r = 0; r < 4; ++r) {
        float p = exp2f(S[r] * SCL);
        ls[r] += p;
        const int il = w * 16 + quad * 4 + r;
        const int jl = fj * 16 + l15;
        sP[il * 128 + (((jl >> 3) ^ (il & 15)) << 3) + (jl & 7)] = (bf16_t)p;
      }
    }

    // wave reads only P rows it wrote -> no barrier needed (per-wave DS ordering)
    bf16x8 pf[4];
    #pragma unroll
    for (int ks = 0; ks < 4; ++ks)
      pf[ks] = *(const bf16x8*)&sP[irow * 128 + (((ks * 4 + quad) ^ l15) << 3)];

    #pragma unroll
    for (int fc = 0; fc < 8; ++fc) {
      const int cr = fc * 16 + l15;
      #pragma unroll
      for (int ks = 0; ks < 4; ++ks) {
        bf16x8 qf = *(const bf16x8*)&sQ[cr * 128 + (((ks * 4 + quad) ^ l15) << 3)];
        U[fc] = __builtin_amdgcn_mfma_f32_16x16x32_bf16(pf[ks], qf, U[fc], 0, 0, 0);
      }
    }
    __syncthreads();
  }

  #pragma unroll
  for (int r = 0; r < 4; ++r) {
    #pragma unroll
    for (int off = 1; off < 16; off <<= 1)
      ls[r] += __shfl_xor(ls[r], off, 64);
  }
  float rls[4];
  #pragma unroll
  for (int r = 0; r < 4; ++r) rls[r] = 1.0f / ls[r];

  // fp32 output: out[b][c][i], lanes write f32x4 along i (coalesced 16B)
  #pragma unroll
  for (int fc = 0; fc < 8; ++fc) {
    const int c = h * 128 + fc * 16 + l15;
    f32x4 v;
    #pragma unroll
    for (int r = 0; r < 4; ++r) v[r] = U[fc][r] * rls[r];
    const long o = ((long)b * 1024 + c) * 2048 + i0 + w * 16 + quad * 4;
    *(f32x4*)&out[o] = v;
  }
}

extern "C" void kernel_launch(void* const* d_in, const int* in_sizes, int n_in,
                              void* d_out, int out_size, void* d_ws, size_t ws_size,
                              hipStream_t stream)
{
  (void)in_sizes; (void)n_in; (void)out_size; (void)ws_size;
  const float* Xq = (const float*)d_in[0];
  const float* Xk = (const float*)d_in[1];
  const float* Wq = (const float*)d_in[2];
  const float* Wk = (const float*)d_in[3];
  const float* Wv = (const float*)d_in[4];
  bf16_t* ws = (bf16_t*)d_ws;
  float* out = (float*)d_out;

  k_wconv<<<dim3(1024, 3), 256, 0, stream>>>(Wq, Wk, Wv, ws);
  k_transpose<<<dim3(32, 16, 8), 256, 0, stream>>>(Xq, Xk, ws);
  k_qkv<<<dim3(16, 8, 12), 256, 0, stream>>>(
      (const float*)d_in[5],  (const float*)d_in[6],  (const float*)d_in[7],  (const float*)d_in[8],
      (const float*)d_in[9],  (const float*)d_in[10], (const float*)d_in[11], (const float*)d_in[12],
      (const float*)d_in[13], (const float*)d_in[14], (const float*)d_in[15], (const float*)d_in[16],
      ws);
  k_attn<<<dim3(16, 8, 4), 512, 0, stream>>>(ws, out);
}

// Round 4
// 292.063 us; speedup vs baseline: 1.1533x; 1.1533x over previous
//
#include <hip/hip_runtime.h>

typedef __bf16 bf16_t;
typedef __bf16 bf16x8 __attribute__((ext_vector_type(8)));
typedef __bf16 bf16x4 __attribute__((ext_vector_type(4)));
typedef float  f32x4  __attribute__((ext_vector_type(4)));

// workspace layout (bf16 element offsets)
#define WB_OFF  0LL          // 3 x 1024 x 1024 bf16 weights (q,k,v)
#define XQT_OFF 3145728LL    // [b][p][c] bf16
#define XKT_OFF 11534336LL
#define Q_OFF   19922944LL   // [b][c][p] bf16
#define KT_OFF  28311552LL   // [b][p][c] bf16
#define VT_OFF  36700160LL   // [b][p][c] bf16
// total: 45088768 elems * 2B = 90.2 MB

__device__ __forceinline__ void gl_lds16(const bf16_t* g, bf16_t* l) {
  __builtin_amdgcn_global_load_lds((const __attribute__((address_space(1))) void*)(g),
                                   (__attribute__((address_space(3))) void*)(l), 16, 0, 0);
}

__device__ __forceinline__ bf16x4 cvt4(f32x4 v) {
  bf16x4 r;
  r[0] = (bf16_t)v[0]; r[1] = (bf16_t)v[1]; r[2] = (bf16_t)v[2]; r[3] = (bf16_t)v[3];
  return r;
}

// ---------------- weight convert: fp32 -> bf16 ----------------
__global__ __launch_bounds__(256) void k_wconv(
    const float* __restrict__ Wq, const float* __restrict__ Wk, const float* __restrict__ Wv,
    bf16_t* __restrict__ ws)
{
  const float* W = blockIdx.y == 0 ? Wq : (blockIdx.y == 1 ? Wk : Wv);
  bf16_t* dst = ws + WB_OFF + (long)blockIdx.y * 1048576;
  const long i = ((long)blockIdx.x * 256 + threadIdx.x) * 4;
  *(bf16x4*)&dst[i] = cvt4(*(const f32x4*)(W + i));
}

// ---------------- transpose+convert: XT[b][p][c] = bf16(X[b][c][p]) ----------------
__global__ __launch_bounds__(256) void k_transpose(
    const float* __restrict__ Xq, const float* __restrict__ Xk, bf16_t* __restrict__ ws)
{
  __shared__ __align__(16) bf16_t t[64 * 72];  // +8 pad per row (16B-aligned rows)
  const int z = blockIdx.z, b = z & 3, ts = z >> 2;
  const float* X = ts ? Xk : Xq;
  bf16_t* XT = ws + (ts ? XKT_OFF : XQT_OFF);
  const int p0 = blockIdx.x * 64, c0 = blockIdx.y * 64;
  const int tid = threadIdx.x;
  const int tx = tid & 15, ty = tid >> 4;  // tx: float4 column, ty: 0..15
  const float* src = X + ((long)b * 1024 + c0) * 2048 + p0;
  #pragma unroll
  for (int hh = 0; hh < 4; ++hh) {
    int c = ty + hh * 16;
    f32x4 v = *(const f32x4*)(src + (long)c * 2048 + tx * 4);
    *(bf16x4*)&t[c * 72 + tx * 4] = cvt4(v);
  }
  __syncthreads();
  bf16_t* dst = XT + ((long)b * 2048 + p0) * 1024 + c0;
  #pragma unroll
  for (int hh = 0; hh < 2; ++hh) {
    int p = (tid >> 3) + hh * 32;  // 0..63
    int cc = tid & 7;
    bf16x8 v;
    #pragma unroll
    for (int j = 0; j < 8; ++j) v[j] = t[(cc * 8 + j) * 72 + p];
    *(bf16x8*)(dst + (long)p * 1024 + cc * 8) = v;
  }
}

// ---------------- QKV GEMM: Y[o][p] = LeakyReLU(BN(W @ X)) ----------------
__global__ __launch_bounds__(256) void k_qkv(
    const float* __restrict__ g1, const float* __restrict__ b1, const float* __restrict__ m1, const float* __restrict__ v1,
    const float* __restrict__ g2, const float* __restrict__ b2, const float* __restrict__ m2, const float* __restrict__ v2,
    const float* __restrict__ g3, const float* __restrict__ b3, const float* __restrict__ m3, const float* __restrict__ v3,
    bf16_t* __restrict__ ws)
{
  __shared__ __align__(16) bf16_t smem[17408];  // staging: a[8192]+b[8192]; epilogue: 128*136
  bf16_t* sa = smem;
  bf16_t* sb = smem + 8192;
  bf16_t* ep = smem;
  __shared__ float sS[128], sBi[128];

  const int tid = threadIdx.x;
  const int z = blockIdx.z, br = z >> 2, b = z & 3;
  const int o0 = blockIdx.y * 128, p0 = blockIdx.x * 128;

  const float *gm, *bt, *mn, *vr;
  const bf16_t *XT;
  bf16_t* dst;
  int tr;
  if (br == 0)      { XT = ws + XQT_OFF; gm = g1; bt = b1; mn = m1; vr = v1; dst = ws + Q_OFF;  tr = 0; }
  else if (br == 1) { XT = ws + XKT_OFF; gm = g2; bt = b2; mn = m2; vr = v2; dst = ws + KT_OFF; tr = 1; }
  else              { XT = ws + XQT_OFF; gm = g3; bt = b3; mn = m3; vr = v3; dst = ws + VT_OFF; tr = 1; }
  const bf16_t* W = ws + WB_OFF + (long)br * 1048576;

  if (tid < 128) {
    float g = gm[o0 + tid], be = bt[o0 + tid];
    float m = mn[o0 + tid], v = vr[o0 + tid];
    float sc = g / sqrtf(v + 1e-5f);
    sS[tid] = sc; sBi[tid] = be - m * sc;
  }

  const int w = tid >> 6, lane = tid & 63, quad = lane >> 4, l15 = lane & 15;
  const int wr = (w >> 1) * 64, wc = (w & 1) * 64;

  f32x4 acc[4][4];
  #pragma unroll
  for (int i = 0; i < 4; ++i)
    #pragma unroll
    for (int j = 0; j < 4; ++j) acc[i][j] = f32x4{0.f, 0.f, 0.f, 0.f};

  const bf16_t* Wb = W + (long)o0 * 1024;
  const bf16_t* Xb = XT + ((long)b * 2048 + p0) * 1024;

  for (int kk = 0; kk < 16; ++kk) {
    __syncthreads();
    const int kof = kk * 64;
    #pragma unroll
    for (int is = 0; is < 4; ++is) {
      int s = (is * 4 + w) * 64 + lane;
      int row = s >> 3, ch = s & 7;
      int col = kof + ((ch ^ (row & 7)) << 3);
      gl_lds16(Wb + (long)row * 1024 + col, &sa[(is * 4 + w) * 512]);
      gl_lds16(Xb + (long)row * 1024 + col, &sb[(is * 4 + w) * 512]);
    }
    __syncthreads();
    #pragma unroll
    for (int ks = 0; ks < 2; ++ks) {
      bf16x8 af[4], bfr[4];
      #pragma unroll
      for (int i = 0; i < 4; ++i) {
        int mm = wr + i * 16 + l15;
        af[i] = *(const bf16x8*)&sa[mm * 64 + (((ks * 4 + quad) ^ (mm & 7)) << 3)];
        int nn = wc + i * 16 + l15;
        bfr[i] = *(const bf16x8*)&sb[nn * 64 + (((ks * 4 + quad) ^ (nn & 7)) << 3)];
      }
      #pragma unroll
      for (int i = 0; i < 4; ++i)
        #pragma unroll
        for (int j = 0; j < 4; ++j)
          acc[i][j] = __builtin_amdgcn_mfma_f32_16x16x32_bf16(af[i], bfr[j], acc[i][j], 0, 0, 0);
    }
  }

  __syncthreads();
  #pragma unroll
  for (int i = 0; i < 4; ++i) {
    #pragma unroll
    for (int j = 0; j < 4; ++j) {
      const int p_l = wc + j * 16 + l15;
      const int ob = wr + i * 16 + quad * 4;
      if (!tr) {
        #pragma unroll
        for (int r = 0; r < 4; ++r) {
          float v = fmaf(acc[i][j][r], sS[ob + r], sBi[ob + r]);
          v = v > 0.f ? v : 0.1f * v;
          ep[(ob + r) * 136 + p_l] = (bf16_t)v;
        }
      } else {
        bf16x4 t4;
        #pragma unroll
        for (int r = 0; r < 4; ++r) {
          float v = fmaf(acc[i][j][r], sS[ob + r], sBi[ob + r]);
          v = v > 0.f ? v : 0.1f * v;
          t4[r] = (bf16_t)v;
        }
        *(bf16x4*)&ep[p_l * 136 + ob] = t4;  // (p_l*136+ob)*2 is 8B-aligned
      }
    }
  }
  __syncthreads();
  #pragma unroll
  for (int pass = 0; pass < 8; ++pass) {
    int row = pass * 16 + (tid >> 4);
    int ch = tid & 15;
    bf16x8 v = *(const bf16x8*)&ep[row * 136 + ch * 8];
    long off;
    if (!tr) off = ((long)b * 1024 + o0 + row) * 2048 + p0 + ch * 8;
    else     off = ((long)b * 2048 + p0 + row) * 1024 + o0 + ch * 8;
    *(bf16x8*)&dst[off] = v;
  }
}

// ---------------- fused attention v2 ----------------
// per block: (b, h, i0-tile of 128). 8 waves. TJ=64 j-tiles, 32 iters.
// K frags resident in VGPRs (loaded once from global). V/Q double-buffered in
// LDS via global_load_lds, prefetch issued after each barrier (one compute
// phase in flight). S computed TRANSPOSED (mfma(V,K)) so each lane holds 4
// j-consecutive P values -> one ds_write_b64 per fj tile; softmax row-sum is a
// single scalar/lane. P round-trips LDS wave-locally (no barrier). LDS = 80 KB
// exactly -> 2 blocks/CU; launch_bounds(512,4) caps VGPR at 128.
__global__ __launch_bounds__(512, 4) void k_attn(const bf16_t* __restrict__ ws, float* __restrict__ out)
{
  __shared__ __align__(16) bf16_t sV[2][8192];   // [j 64][c 128] swizzled
  __shared__ __align__(16) bf16_t sQ[2][8192];   // [c 128][j 64] swizzled
  __shared__ __align__(16) bf16_t sP[8192];      // [i 128][j 64] swizzled

  const int tid = threadIdx.x, w = tid >> 6, lane = tid & 63, quad = lane >> 4, l15 = lane & 15;
  const int i0 = blockIdx.x * 128, h = blockIdx.y, b = blockIdx.z;

  const bf16_t* KTb = ws + KT_OFF + ((long)b * 2048 + i0) * 1024 + h * 128;
  const bf16_t* VTb = ws + VT_OFF + ((long)b * 2048) * 1024 + h * 128;
  const bf16_t* Qb  = ws + Q_OFF  + ((long)b * 1024 + h * 128) * 2048;

  const int irow = w * 16 + l15;   // this wave's 16 i-rows

  // K frags direct from global -> VGPRs, resident all 32 iters.
  // B-frag for QK^T-transposed: n = i (l15), k = c = (ks*4+quad)*8 + e
  bf16x8 af[4];
  #pragma unroll
  for (int ks = 0; ks < 4; ++ks)
    af[ks] = *(const bf16x8*)(KTb + (long)irow * 1024 + (ks * 4 + quad) * 8);

  f32x4 U[8];
  #pragma unroll
  for (int f = 0; f < 8; ++f) U[f] = f32x4{0.f, 0.f, 0.f, 0.f};
  float ls = 0.f;

  const float SCL = 1.4426950408889634f * 0.08838834764831843f;  // log2(e)/sqrt(128)

  // ---- stage tile jt into buffer bb (swizzle on GLOBAL col; LDS stays lane-contiguous)
  #define STAGE(jt, bb)                                                               \
    {                                                                                 \
      const int j0_ = (jt) * 64;                                                      \
      _Pragma("unroll")                                                               \
      for (int rnd = 0; rnd < 2; ++rnd) {                                             \
        int s = rnd * 512 + tid;                                                      \
        int vrow = s >> 4, vch = s & 15;                                              \
        gl_lds16(VTb + (long)(j0_ + vrow) * 1024 + ((vch ^ (vrow & 15)) << 3),        \
                 &sV[bb][s * 8]);                                                     \
        int qrow = s >> 3, qch = s & 7;                                               \
        gl_lds16(Qb + (long)qrow * 2048 + j0_ + ((qch ^ (qrow & 7)) << 3),            \
                 &sQ[bb][s * 8]);                                                     \
      }                                                                               \
    }

  STAGE(0, 0);
  __syncthreads();

  for (int jt = 0; jt < 32; ++jt) {
    const int cur = jt & 1;
    if (jt < 31) STAGE(jt + 1, cur ^ 1);   // prefetch: in flight across this compute phase

    // ---- S^T = V^T K : D[m=j_loc, n=i_loc], per fj tile of 16 j
    #pragma unroll
    for (int fj = 0; fj < 4; ++fj) {
      f32x4 S = f32x4{0.f, 0.f, 0.f, 0.f};
      const int jr = fj * 16 + l15;
      #pragma unroll
      for (int ks = 0; ks < 4; ++ks) {
        bf16x8 vfr = *(const bf16x8*)&sV[cur][jr * 128 + (((ks * 4 + quad) ^ (jr & 15)) << 3)];
        S = __builtin_amdgcn_mfma_f32_16x16x32_bf16(vfr, af[ks], S, 0, 0, 0);
      }
      // lane holds S^T rows j = fj*16 + quad*4 + r, col i = w*16 + l15
      bf16x4 p4;
      #pragma unroll
      for (int r = 0; r < 4; ++r) {
        float p = exp2f(S[r] * SCL);
        ls += p;
        p4[r] = (bf16_t)p;
      }
      const int i = w * 16 + l15;
      const int jl = fj * 16 + quad * 4;
      *(bf16x4*)&sP[i * 64 + (((jl >> 3) ^ (i & 7)) << 3) + (jl & 7)] = p4;
    }

    // ---- P A-frags (wave-local rows; per-wave DS ordering suffices, no barrier)
    bf16x8 pf[2];
    #pragma unroll
    for (int ks = 0; ks < 2; ++ks)
      pf[ks] = *(const bf16x8*)&sP[irow * 64 + (((ks * 4 + quad) ^ (irow & 7)) << 3)];

    // ---- U += P Q^T : D[m=i_loc, n=c_loc]
    #pragma unroll
    for (int fc = 0; fc < 8; ++fc) {
      const int c = fc * 16 + l15;
      #pragma unroll
      for (int ks = 0; ks < 2; ++ks) {
        bf16x8 qf = *(const bf16x8*)&sQ[cur][c * 64 + (((ks * 4 + quad) ^ (c & 7)) << 3)];
        U[fc] = __builtin_amdgcn_mfma_f32_16x16x32_bf16(pf[ks], qf, U[fc], 0, 0, 0);
      }
    }
    __syncthreads();   // releases buf[cur] for jt+2's stage; drains jt+1's prefetch
  }

  // ---- softmax denominators: lane has partial sum for row i = w*16 + l15
  ls += __shfl_xor(ls, 16, 64);
  ls += __shfl_xor(ls, 32, 64);
  float* lsum = (float*)&sP[(w * 16) * 64];   // wave-local scratch (128 B row)
  if (quad == 0) lsum[l15] = ls;
  f32x4 rl4 = *(const f32x4*)&lsum[quad * 4]; // ls for i_loc = quad*4 + r

  // ---- out[b][c][i0 + w*16 + quad*4 + r], fp32, f32x4 along i (coalesced)
  #pragma unroll
  for (int fc = 0; fc < 8; ++fc) {
    const int c = h * 128 + fc * 16 + l15;
    f32x4 v;
    #pragma unroll
    for (int r = 0; r < 4; ++r) v[r] = U[fc][r] / rl4[r];
    const long o = ((long)b * 1024 + c) * 2048 + i0 + w * 16 + quad * 4;
    *(f32x4*)&out[o] = v;
  }
}

extern "C" void kernel_launch(void* const* d_in, const int* in_sizes, int n_in,
                              void* d_out, int out_size, void* d_ws, size_t ws_size,
                              hipStream_t stream)
{
  (void)in_sizes; (void)n_in; (void)out_size; (void)ws_size;
  const float* Xq = (const float*)d_in[0];
  const float* Xk = (const float*)d_in[1];
  const float* Wq = (const float*)d_in[2];
  const float* Wk = (const float*)d_in[3];
  const float* Wv = (const float*)d_in[4];
  bf16_t* ws = (bf16_t*)d_ws;
  float* out = (float*)d_out;

  k_wconv<<<dim3(1024, 3), 256, 0, stream>>>(Wq, Wk, Wv, ws);
  k_transpose<<<dim3(32, 16, 8), 256, 0, stream>>>(Xq, Xk, ws);
  k_qkv<<<dim3(16, 8, 12), 256, 0, stream>>>(
      (const float*)d_in[5],  (const float*)d_in[6],  (const float*)d_in[7],  (const float*)d_in[8],
      (const float*)d_in[9],  (const float*)d_in[10], (const float*)d_in[11], (const float*)d_in[12],
      (const float*)d_in[13], (const float*)d_in[14], (const float*)d_in[15], (const float*)d_in[16],
      ws);
  k_attn<<<dim3(16, 8, 4), 512, 0, stream>>>(ws, out);
}